// Round 11
// baseline (324.566 us; speedup 1.0000x reference)
//
#include <hip/hip_runtime.h>
#include <cstdint>
#include <cstddef>

typedef unsigned int uint;
typedef unsigned short ushort;

// bf16 helpers: RNE pack, shift-unpack (exact)
__device__ __forceinline__ ushort f2bf(float f) {
    uint u = __float_as_uint(f);
    u = u + 0x7FFFu + ((u >> 16) & 1u);
    return (ushort)(u >> 16);
}
__device__ __forceinline__ float bf_lo(uint u) { return __uint_as_float((u & 0xFFFFu) << 16); }
__device__ __forceinline__ float bf_hi(uint u) { return __uint_as_float(u & 0xFFFF0000u); }

// ---------------- CSR build ----------------
// (coop grid.sync costs ~60-70us/barrier on MI355X — measured round 7 — keep
//  separate small kernels. Rank trick from round 9: count's atomicAdd RETURN
//  is the edge's rank -> scatter has no atomics. Edge weight dinv[s]*dinv[d]
//  fused into the CSR payload int2 {src, w_bits}.)

__global__ __launch_bounds__(256) void k_count(const int* __restrict__ dst,
                                               int* __restrict__ cnt,
                                               int* __restrict__ rank, int E) {
    int e4 = (blockIdx.x * 256 + threadIdx.x) * 4;
    if (e4 + 3 < E) {
        int4 d = *reinterpret_cast<const int4*>(&dst[e4]);
        int4 r;
        r.x = atomicAdd(&cnt[d.x], 1);
        r.y = atomicAdd(&cnt[d.y], 1);
        r.z = atomicAdd(&cnt[d.z], 1);
        r.w = atomicAdd(&cnt[d.w], 1);
        *reinterpret_cast<int4*>(&rank[e4]) = r;   // coalesced 16B
    } else {
        for (int e = e4; e < E; e++)
            rank[e] = atomicAdd(&cnt[dst[e]], 1);
    }
}

// one kernel: block b sums cnt[0..b*256) for its prefix (L2-resident, ~5M
// coalesced reads total), then in-chunk scan -> rowptr + dinv.
__global__ __launch_bounds__(256) void k_scan_write(const int* __restrict__ cnt,
                                                    int* __restrict__ rowptr,
                                                    float* __restrict__ dinv, int n) {
    __shared__ int sd[256];
    int t = threadIdx.x;
    int base = blockIdx.x * 256;
    // 1) prefix = sum of cnt[0..base)
    int acc = 0;
    for (int i = t; i < base; i += 256) acc += cnt[i];
    sd[t] = acc;
    __syncthreads();
    for (int s = 128; s > 0; s >>= 1) {
        if (t < s) sd[t] += sd[t + s];
        __syncthreads();
    }
    int prefix = sd[0];
    __syncthreads();
    // 2) in-chunk exclusive scan
    int i = base + t;
    int v = (i < n) ? cnt[i] : 0;
    sd[t] = v;
    __syncthreads();
    for (int off = 1; off < 256; off <<= 1) {
        int add = (t >= off) ? sd[t - off] : 0;
        __syncthreads();
        sd[t] += add;
        __syncthreads();
    }
    int excl = sd[t] - v + prefix;
    if (i < n) {
        rowptr[i] = excl;
        dinv[i] = rsqrtf((float)v + 1.0f);  // +1 self-loop, always > 0
    }
}

// no atomics: pos = rowptr[d] + rank[e]; payload = {src, bits(dinv[s]*dinv[d])}
__global__ __launch_bounds__(256) void k_scatter(const int* __restrict__ src,
                                                 const int* __restrict__ dst,
                                                 const int* __restrict__ rowptr,
                                                 const int* __restrict__ rank,
                                                 const float* __restrict__ dinv,
                                                 int2* __restrict__ eSW, int E) {
    int e4 = (blockIdx.x * 256 + threadIdx.x) * 4;
    if (e4 + 3 < E) {
        int4 s = *reinterpret_cast<const int4*>(&src[e4]);
        int4 d = *reinterpret_cast<const int4*>(&dst[e4]);
        int4 r = *reinterpret_cast<const int4*>(&rank[e4]);
        int2 p0, p1, p2, p3;
        p0.x = s.x; p0.y = __float_as_int(dinv[s.x] * dinv[d.x]);
        p1.x = s.y; p1.y = __float_as_int(dinv[s.y] * dinv[d.y]);
        p2.x = s.z; p2.y = __float_as_int(dinv[s.z] * dinv[d.z]);
        p3.x = s.w; p3.y = __float_as_int(dinv[s.w] * dinv[d.w]);
        eSW[rowptr[d.x] + r.x] = p0;
        eSW[rowptr[d.y] + r.y] = p1;
        eSW[rowptr[d.z] + r.z] = p2;
        eSW[rowptr[d.w] + r.w] = p3;
    } else {
        for (int e = e4; e < E; e++) {
            int s = src[e], d = dst[e];
            int2 pp; pp.x = s; pp.y = __float_as_int(dinv[s] * dinv[d]);
            eSW[rowptr[d] + rank[e]] = pp;
        }
    }
}

// ---------------- GEMM: C_bf16[n x 128] = A[n x 128] @ W[128 x 128] ---------
// 256 threads = 4 waves; tile 64 rows x 128 cols. K in 4 chunks of 32.
// A staged transposed As[k][row]; W chunk flat. Thread: 4 rows x 8 cols.
// Two variants: fp32-A (layer 1 input x) and bf16-A (layer 2 input h1).

#define AP 68  // padded pitch for As rows (floats)

__global__ __launch_bounds__(256, 4) void k_gemm128_f32(const float* __restrict__ A,
                                                        const float* __restrict__ Wg,
                                                        ushort* __restrict__ C, int nrows) {
    __shared__ float As[32 * AP];
    __shared__ float Ws[32 * 128];
    const int tid = threadIdx.x;
    const int tc = tid & 15;
    const int tr = tid >> 4;
    const int r0 = blockIdx.x * 64;

    float acc[4][8];
#pragma unroll
    for (int j = 0; j < 4; j++)
#pragma unroll
        for (int c = 0; c < 8; c++) acc[j][c] = 0.0f;

    const float4* A4 = reinterpret_cast<const float4*>(A);
    const float4* Wg4 = reinterpret_cast<const float4*>(Wg);
    float4* Ws4 = reinterpret_cast<float4*>(Ws);

    const int srow = tid >> 3;       // 0..31 row within staging pass
    const int sk4 = tid & 7;

    for (int kc = 0; kc < 4; kc++) {
#pragma unroll
        for (int i = 0; i < 4; i++) Ws4[tid + 256 * i] = Wg4[kc * 1024 + tid + 256 * i];
#pragma unroll
        for (int pass = 0; pass < 2; pass++) {
            int rl = srow + pass * 32;
            int rg = r0 + rl;
            if (rg > nrows - 1) rg = nrows - 1;
            float4 av = A4[(size_t)rg * 32 + kc * 8 + sk4];
            int kb = sk4 * 4;
            As[(kb + 0) * AP + rl] = av.x;
            As[(kb + 1) * AP + rl] = av.y;
            As[(kb + 2) * AP + rl] = av.z;
            As[(kb + 3) * AP + rl] = av.w;
        }
        __syncthreads();

#pragma unroll 4
        for (int k = 0; k < 32; k++) {
            const float4 a = *reinterpret_cast<const float4*>(&As[k * AP + tr * 4]);
            const float4 w0 = *reinterpret_cast<const float4*>(&Ws[k * 128 + tc * 8]);
            const float4 w1 = *reinterpret_cast<const float4*>(&Ws[k * 128 + tc * 8 + 4]);
            const float av4[4] = {a.x, a.y, a.z, a.w};
            const float wv[8] = {w0.x, w0.y, w0.z, w0.w, w1.x, w1.y, w1.z, w1.w};
#pragma unroll
            for (int j = 0; j < 4; j++)
#pragma unroll
                for (int c = 0; c < 8; c++)
                    acc[j][c] = fmaf(av4[j], wv[c], acc[j][c]);
        }
        __syncthreads();
    }

#pragma unroll
    for (int j = 0; j < 4; j++) {
        const int r = r0 + tr * 4 + j;
        if (r < nrows) {
            uint4 o;
            o.x = (uint)f2bf(acc[j][0]) | ((uint)f2bf(acc[j][1]) << 16);
            o.y = (uint)f2bf(acc[j][2]) | ((uint)f2bf(acc[j][3]) << 16);
            o.z = (uint)f2bf(acc[j][4]) | ((uint)f2bf(acc[j][5]) << 16);
            o.w = (uint)f2bf(acc[j][6]) | ((uint)f2bf(acc[j][7]) << 16);
            *reinterpret_cast<uint4*>(&C[(size_t)r * 128 + tc * 8]) = o;
        }
    }
}

__global__ __launch_bounds__(256, 4) void k_gemm128_bf16(const ushort* __restrict__ A,
                                                         const float* __restrict__ Wg,
                                                         ushort* __restrict__ C, int nrows) {
    __shared__ float As[32 * AP];
    __shared__ float Ws[32 * 128];
    const int tid = threadIdx.x;
    const int tc = tid & 15;
    const int tr = tid >> 4;
    const int r0 = blockIdx.x * 64;

    float acc[4][8];
#pragma unroll
    for (int j = 0; j < 4; j++)
#pragma unroll
        for (int c = 0; c < 8; c++) acc[j][c] = 0.0f;

    const uint4* A4 = reinterpret_cast<const uint4*>(A);   // row = 16 uint4
    const float4* Wg4 = reinterpret_cast<const float4*>(Wg);
    float4* Ws4 = reinterpret_cast<float4*>(Ws);

    const int srow = tid >> 2;       // 0..63, single pass
    const int sk = tid & 3;          // uint4 index within 32-k chunk (4 per chunk)

    for (int kc = 0; kc < 4; kc++) {
#pragma unroll
        for (int i = 0; i < 4; i++) Ws4[tid + 256 * i] = Wg4[kc * 1024 + tid + 256 * i];
        {
            int rg = r0 + srow;
            if (rg > nrows - 1) rg = nrows - 1;
            uint4 u = A4[(size_t)rg * 16 + kc * 4 + sk];
            int kb = sk * 8;
            As[(kb + 0) * AP + srow] = bf_lo(u.x);
            As[(kb + 1) * AP + srow] = bf_hi(u.x);
            As[(kb + 2) * AP + srow] = bf_lo(u.y);
            As[(kb + 3) * AP + srow] = bf_hi(u.y);
            As[(kb + 4) * AP + srow] = bf_lo(u.z);
            As[(kb + 5) * AP + srow] = bf_hi(u.z);
            As[(kb + 6) * AP + srow] = bf_lo(u.w);
            As[(kb + 7) * AP + srow] = bf_hi(u.w);
        }
        __syncthreads();

#pragma unroll 4
        for (int k = 0; k < 32; k++) {
            const float4 a = *reinterpret_cast<const float4*>(&As[k * AP + tr * 4]);
            const float4 w0 = *reinterpret_cast<const float4*>(&Ws[k * 128 + tc * 8]);
            const float4 w1 = *reinterpret_cast<const float4*>(&Ws[k * 128 + tc * 8 + 4]);
            const float av4[4] = {a.x, a.y, a.z, a.w};
            const float wv[8] = {w0.x, w0.y, w0.z, w0.w, w1.x, w1.y, w1.z, w1.w};
#pragma unroll
            for (int j = 0; j < 4; j++)
#pragma unroll
                for (int c = 0; c < 8; c++)
                    acc[j][c] = fmaf(av4[j], wv[c], acc[j][c]);
        }
        __syncthreads();
    }

#pragma unroll
    for (int j = 0; j < 4; j++) {
        const int r = r0 + tr * 4 + j;
        if (r < nrows) {
            uint4 o;
            o.x = (uint)f2bf(acc[j][0]) | ((uint)f2bf(acc[j][1]) << 16);
            o.y = (uint)f2bf(acc[j][2]) | ((uint)f2bf(acc[j][3]) << 16);
            o.z = (uint)f2bf(acc[j][4]) | ((uint)f2bf(acc[j][5]) << 16);
            o.w = (uint)f2bf(acc[j][6]) | ((uint)f2bf(acc[j][7]) << 16);
            *reinterpret_cast<uint4*>(&C[(size_t)r * 128 + tc * 8]) = o;
        }
    }
}

// ---------------- Gather, quarter-wave: 4 edges per VMEM instruction --------
// wave = 1 dst node. lane = (q, sub): quarter q handles edge j+q; lane loads
// uint4 = 8 bf16 cols (sub*8..sub*8+7). One row-load instr fetches FOUR rows
// (1 KB). Two-level __shfl_xor(16,32) combines quarters. Output bf16.

__global__ __launch_bounds__(256) void k_gather(const ushort* __restrict__ hw,
                                                const float* __restrict__ dinv,
                                                const int* __restrict__ rowptr,
                                                const int* __restrict__ cnt,
                                                const int2* __restrict__ eSW,
                                                const float* __restrict__ bias,
                                                ushort* __restrict__ outp, int n) {
    int wave = threadIdx.x >> 6;
    int lane = threadIdx.x & 63;
    int q = lane >> 4;
    int sub = lane & 15;
    int node = blockIdx.x * 4 + wave;
    if (node >= n) return;

    float di = dinv[node];
    int start = rowptr[node];
    int deg = cnt[node];

    const uint4* base4 = reinterpret_cast<const uint4*>(hw);
    float a[8];
    {   // self-loop: quarter 0 only
        uint4 u = base4[(size_t)node * 16 + sub];
        float sw = (q == 0) ? di * di : 0.0f;
        a[0] = bf_lo(u.x) * sw; a[1] = bf_hi(u.x) * sw;
        a[2] = bf_lo(u.y) * sw; a[3] = bf_hi(u.y) * sw;
        a[4] = bf_lo(u.z) * sw; a[5] = bf_hi(u.z) * sw;
        a[6] = bf_lo(u.w) * sw; a[7] = bf_hi(u.w) * sw;
    }

    int j = 0;
    for (; j + 8 <= deg; j += 8) {           // 2 quads in flight
        int2 e0 = eSW[start + j + q];
        int2 e1 = eSW[start + j + 4 + q];
        uint4 u0 = base4[(size_t)e0.x * 16 + sub];
        uint4 u1 = base4[(size_t)e1.x * 16 + sub];
        float w0 = __int_as_float(e0.y);
        float w1 = __int_as_float(e1.y);
        a[0] = fmaf(bf_lo(u0.x), w0, a[0]); a[1] = fmaf(bf_hi(u0.x), w0, a[1]);
        a[2] = fmaf(bf_lo(u0.y), w0, a[2]); a[3] = fmaf(bf_hi(u0.y), w0, a[3]);
        a[4] = fmaf(bf_lo(u0.z), w0, a[4]); a[5] = fmaf(bf_hi(u0.z), w0, a[5]);
        a[6] = fmaf(bf_lo(u0.w), w0, a[6]); a[7] = fmaf(bf_hi(u0.w), w0, a[7]);
        a[0] = fmaf(bf_lo(u1.x), w1, a[0]); a[1] = fmaf(bf_hi(u1.x), w1, a[1]);
        a[2] = fmaf(bf_lo(u1.y), w1, a[2]); a[3] = fmaf(bf_hi(u1.y), w1, a[3]);
        a[4] = fmaf(bf_lo(u1.z), w1, a[4]); a[5] = fmaf(bf_hi(u1.z), w1, a[5]);
        a[6] = fmaf(bf_lo(u1.w), w1, a[6]); a[7] = fmaf(bf_hi(u1.w), w1, a[7]);
    }
    for (; j < deg; j += 4) {                // tail quads, predicated
        int idx = j + q;
        bool ok = idx < deg;
        int2 e = eSW[start + (ok ? idx : deg - 1)];
        float w = ok ? __int_as_float(e.y) : 0.0f;
        uint4 u = base4[(size_t)e.x * 16 + sub];
        a[0] = fmaf(bf_lo(u.x), w, a[0]); a[1] = fmaf(bf_hi(u.x), w, a[1]);
        a[2] = fmaf(bf_lo(u.y), w, a[2]); a[3] = fmaf(bf_hi(u.y), w, a[3]);
        a[4] = fmaf(bf_lo(u.z), w, a[4]); a[5] = fmaf(bf_hi(u.z), w, a[5]);
        a[6] = fmaf(bf_lo(u.w), w, a[6]); a[7] = fmaf(bf_hi(u.w), w, a[7]);
    }

#pragma unroll
    for (int k = 0; k < 8; k++) {
        a[k] += __shfl_xor(a[k], 16);
        a[k] += __shfl_xor(a[k], 32);
    }

    if (q == 0) {
        float4 b0 = reinterpret_cast<const float4*>(bias)[sub * 2];
        float4 b1 = reinterpret_cast<const float4*>(bias)[sub * 2 + 1];
        float r0 = fmaxf(a[0] + b0.x, 0.0f), r1 = fmaxf(a[1] + b0.y, 0.0f);
        float r2 = fmaxf(a[2] + b0.z, 0.0f), r3 = fmaxf(a[3] + b0.w, 0.0f);
        float r4 = fmaxf(a[4] + b1.x, 0.0f), r5 = fmaxf(a[5] + b1.y, 0.0f);
        float r6 = fmaxf(a[6] + b1.z, 0.0f), r7 = fmaxf(a[7] + b1.w, 0.0f);
        uint4 o;
        o.x = (uint)f2bf(r0) | ((uint)f2bf(r1) << 16);
        o.y = (uint)f2bf(r2) | ((uint)f2bf(r3) << 16);
        o.z = (uint)f2bf(r4) | ((uint)f2bf(r5) << 16);
        o.w = (uint)f2bf(r6) | ((uint)f2bf(r7) << 16);
        reinterpret_cast<uint4*>(outp)[(size_t)node * 16 + sub] = o;
    }
}

// ---------------- Gather #2 fused with max-pool (same structure) ------------

__global__ __launch_bounds__(256) void k_gather_pool(const ushort* __restrict__ hw,
                                                     const float* __restrict__ dinv,
                                                     const int* __restrict__ rowptr,
                                                     const int* __restrict__ cnt,
                                                     const int2* __restrict__ eSW,
                                                     const float* __restrict__ bias,
                                                     int* __restrict__ pooledPart, int n) {
    __shared__ int smax[128];
    int tid = threadIdx.x;
    int wave = tid >> 6;
    int lane = tid & 63;
    int q = lane >> 4;
    int sub = lane & 15;
    if (tid < 128) smax[tid] = 0;
    __syncthreads();

    int node = blockIdx.x * 4 + wave;
    if (node < n) {
        float di = dinv[node];
        int start = rowptr[node];
        int deg = cnt[node];

        const uint4* base4 = reinterpret_cast<const uint4*>(hw);
        float a[8];
        {
            uint4 u = base4[(size_t)node * 16 + sub];
            float sw = (q == 0) ? di * di : 0.0f;
            a[0] = bf_lo(u.x) * sw; a[1] = bf_hi(u.x) * sw;
            a[2] = bf_lo(u.y) * sw; a[3] = bf_hi(u.y) * sw;
            a[4] = bf_lo(u.z) * sw; a[5] = bf_hi(u.z) * sw;
            a[6] = bf_lo(u.w) * sw; a[7] = bf_hi(u.w) * sw;
        }

        int j = 0;
        for (; j + 8 <= deg; j += 8) {
            int2 e0 = eSW[start + j + q];
            int2 e1 = eSW[start + j + 4 + q];
            uint4 u0 = base4[(size_t)e0.x * 16 + sub];
            uint4 u1 = base4[(size_t)e1.x * 16 + sub];
            float w0 = __int_as_float(e0.y);
            float w1 = __int_as_float(e1.y);
            a[0] = fmaf(bf_lo(u0.x), w0, a[0]); a[1] = fmaf(bf_hi(u0.x), w0, a[1]);
            a[2] = fmaf(bf_lo(u0.y), w0, a[2]); a[3] = fmaf(bf_hi(u0.y), w0, a[3]);
            a[4] = fmaf(bf_lo(u0.z), w0, a[4]); a[5] = fmaf(bf_hi(u0.z), w0, a[5]);
            a[6] = fmaf(bf_lo(u0.w), w0, a[6]); a[7] = fmaf(bf_hi(u0.w), w0, a[7]);
            a[0] = fmaf(bf_lo(u1.x), w1, a[0]); a[1] = fmaf(bf_hi(u1.x), w1, a[1]);
            a[2] = fmaf(bf_lo(u1.y), w1, a[2]); a[3] = fmaf(bf_hi(u1.y), w1, a[3]);
            a[4] = fmaf(bf_lo(u1.z), w1, a[4]); a[5] = fmaf(bf_hi(u1.z), w1, a[5]);
            a[6] = fmaf(bf_lo(u1.w), w1, a[6]); a[7] = fmaf(bf_hi(u1.w), w1, a[7]);
        }
        for (; j < deg; j += 4) {
            int idx = j + q;
            bool ok = idx < deg;
            int2 e = eSW[start + (ok ? idx : deg - 1)];
            float w = ok ? __int_as_float(e.y) : 0.0f;
            uint4 u = base4[(size_t)e.x * 16 + sub];
            a[0] = fmaf(bf_lo(u.x), w, a[0]); a[1] = fmaf(bf_hi(u.x), w, a[1]);
            a[2] = fmaf(bf_lo(u.y), w, a[2]); a[3] = fmaf(bf_hi(u.y), w, a[3]);
            a[4] = fmaf(bf_lo(u.z), w, a[4]); a[5] = fmaf(bf_hi(u.z), w, a[5]);
            a[6] = fmaf(bf_lo(u.w), w, a[6]); a[7] = fmaf(bf_hi(u.w), w, a[7]);
        }

#pragma unroll
        for (int k = 0; k < 8; k++) {
            a[k] += __shfl_xor(a[k], 16);
            a[k] += __shfl_xor(a[k], 32);
        }

        if (q == 0) {
            float4 b0 = reinterpret_cast<const float4*>(bias)[sub * 2];
            float4 b1 = reinterpret_cast<const float4*>(bias)[sub * 2 + 1];
            float r[8];
            r[0] = fmaxf(a[0] + b0.x, 0.0f); r[1] = fmaxf(a[1] + b0.y, 0.0f);
            r[2] = fmaxf(a[2] + b0.z, 0.0f); r[3] = fmaxf(a[3] + b0.w, 0.0f);
            r[4] = fmaxf(a[4] + b1.x, 0.0f); r[5] = fmaxf(a[5] + b1.y, 0.0f);
            r[6] = fmaxf(a[6] + b1.z, 0.0f); r[7] = fmaxf(a[7] + b1.w, 0.0f);
#pragma unroll
            for (int k = 0; k < 8; k++)
                atomicMax(&smax[sub * 8 + k], __float_as_int(r[k]));  // >=0: int max ok
        }
    }
    __syncthreads();
    if (tid < 128) pooledPart[(size_t)blockIdx.x * 128 + tid] = smax[tid];
}

// ---------------- pool reduce + fc, fused (last-block-done ticket) ----------
// pooledBits needs NO memset: 0xAA poison = negative int, all values >= 0 win.
// ticket IS zeroed (shares the cnt memset region).

__global__ __launch_bounds__(256) void k_pool2fc(const int* __restrict__ pooledPart,
                                                 int* __restrict__ pooledBits,
                                                 int* __restrict__ ticket,
                                                 const float* __restrict__ Wfc,
                                                 const float* __restrict__ bfc,
                                                 float* __restrict__ out, int nPart) {
    __shared__ int smax[128];
    __shared__ int isLast;
    int tid = threadIdx.x;
    int c = tid & 127;
    int rh = tid >> 7;
    if (tid < 128) smax[tid] = 0;
    __syncthreads();
    int m = 0;
    for (int p = blockIdx.x * 2 + rh; p < nPart; p += gridDim.x * 2) {
        int v = pooledPart[(size_t)p * 128 + c];
        m = v > m ? v : m;   // post-ReLU bits: int compare == float compare
    }
    atomicMax(&smax[c], m);
    __syncthreads();
    if (tid < 128) atomicMax(&pooledBits[tid], smax[tid]);
    __threadfence();
    if (tid == 0) isLast = (atomicAdd(ticket, 1) == (int)gridDim.x - 1) ? 1 : 0;
    __syncthreads();
    if (isLast) {
        __threadfence();
        if (tid < 128) smax[tid] = atomicMax(&pooledBits[tid], 0);  // coherent read
        __syncthreads();
        if (tid < 64) {
            float acc = bfc[tid];
            for (int k = 0; k < 128; k++)
                acc = fmaf(__int_as_float(smax[k]), Wfc[k * 64 + tid], acc);
            out[tid] = acc;
        }
    }
}

// ---------------- launch ----------------

extern "C" void kernel_launch(void* const* d_in, const int* in_sizes, int n_in,
                              void* d_out, int out_size, void* d_ws, size_t ws_size,
                              hipStream_t stream) {
    const float* x   = (const float*)d_in[0];
    const int* edges = (const int*)d_in[1];
    const float* W1  = (const float*)d_in[2];
    const float* b1  = (const float*)d_in[3];
    const float* W2  = (const float*)d_in[4];
    const float* b2  = (const float*)d_in[5];
    const float* Wfc = (const float*)d_in[6];
    const float* bfc = (const float*)d_in[7];
    float* out = (float*)d_out;

    const int N = in_sizes[0] / 128;
    const int E = in_sizes[1] / 2;
    const int* esrc_in = edges;       // edge_index[0]
    const int* edst_in = edges + E;   // edge_index[1]

    // workspace layout (256B aligned chunks)
    auto align256 = [](size_t v) { return (v + 255) & ~(size_t)255; };
    char* p = (char*)d_ws;
    size_t off = 0;
    int* cnt      = (int*)(p + off); off += (size_t)N * 4;
    int* ticket   = (int*)(p + off); off = align256(off + 4);      // zeroed with cnt
    int* rowptr   = (int*)(p + off); off = align256(off + (size_t)N * 4);
    int* rank     = (int*)(p + off); off = align256(off + (size_t)E * 4);
    float* dinv   = (float*)(p + off); off = align256(off + (size_t)N * 4);
    int* pooled   = (int*)(p + off); off = align256(off + 128 * 4);
    int2* eSW     = (int2*)(p + off); off = align256(off + (size_t)E * 8);
    ushort* hwbuf = (ushort*)(p + off); off = align256(off + (size_t)N * 128 * 2);  // bf16 hw
    ushort* h1buf = (ushort*)(p + off); off = align256(off + (size_t)N * 128 * 2);  // bf16 h1
    (void)ws_size; (void)n_in; (void)out_size;

    const int EB4 = (E / 4 + 255) / 256;  // edge blocks, 4 edges/thread
    const int NB = (N + 255) / 256;       // node blocks
    const int GB = (N + 63) / 64;         // gemm blocks (64 rows each)
    const int HB = (N + 3) / 4;           // gather blocks (4 nodes each)

    int* pooledPart = (int*)h1buf;        // reuse: 2nd gather no longer writes h

    hipMemsetAsync(cnt, 0, (size_t)N * 4 + 4, stream);  // cnt + ticket

    k_count<<<EB4, 256, 0, stream>>>(edst_in, cnt, rank, E);
    k_scan_write<<<NB, 256, 0, stream>>>(cnt, rowptr, dinv, N);
    k_scatter<<<EB4, 256, 0, stream>>>(esrc_in, edst_in, rowptr, rank, dinv, eSW, E);

    // layer 1
    k_gemm128_f32<<<GB, 256, 0, stream>>>(x, W1, hwbuf, N);
    k_gather<<<HB, 256, 0, stream>>>(hwbuf, dinv, rowptr, cnt, eSW, b1, h1buf, N);
    // layer 2
    k_gemm128_bf16<<<GB, 256, 0, stream>>>(h1buf, W2, hwbuf, N);
    k_gather_pool<<<HB, 256, 0, stream>>>(hwbuf, dinv, rowptr, cnt, eSW, b2, pooledPart, N);

    // pool reduce + fc (fused)
    k_pool2fc<<<128, 256, 0, stream>>>(pooledPart, pooled, ticket, Wfc, bfc, out, HB);
}

// Round 12
// 309.221 us; speedup vs baseline: 1.0496x; 1.0496x over previous
//
#include <hip/hip_runtime.h>
#include <cstdint>
#include <cstddef>

typedef unsigned int uint;
typedef unsigned short ushort;

// bf16 helpers: RNE pack, shift-unpack (exact)
__device__ __forceinline__ ushort f2bf(float f) {
    uint u = __float_as_uint(f);
    u = u + 0x7FFFu + ((u >> 16) & 1u);
    return (ushort)(u >> 16);
}
__device__ __forceinline__ float bf_lo(uint u) { return __uint_as_float((u & 0xFFFFu) << 16); }
__device__ __forceinline__ float bf_hi(uint u) { return __uint_as_float(u & 0xFFFF0000u); }

// ---------------- CSR build ----------------
// (coop grid.sync ~60-70us/barrier on MI355X (round 7) — separate kernels.
//  Rank trick (round 9): count's atomicAdd RETURN is the edge's rank ->
//  scatter has no atomics. Edge weight dinv[s]*dinv[d] fused into payload.
//  Round 11 lesson: do NOT replace the bsum 2-kernel scan with a per-block
//  serial prefix over cnt — the last block's ~N/256 latency-chained loop
//  added ~15us. Keep k_block_reduce + bsum-reduce-in-scan.)

__global__ __launch_bounds__(256) void k_count(const int* __restrict__ dst,
                                               int* __restrict__ cnt,
                                               int* __restrict__ rank, int E) {
    int e4 = (blockIdx.x * 256 + threadIdx.x) * 4;
    if (e4 + 3 < E) {
        int4 d = *reinterpret_cast<const int4*>(&dst[e4]);
        int4 r;
        r.x = atomicAdd(&cnt[d.x], 1);
        r.y = atomicAdd(&cnt[d.y], 1);
        r.z = atomicAdd(&cnt[d.z], 1);
        r.w = atomicAdd(&cnt[d.w], 1);
        *reinterpret_cast<int4*>(&rank[e4]) = r;   // coalesced 16B
    } else {
        for (int e = e4; e < E; e++)
            rank[e] = atomicAdd(&cnt[dst[e]], 1);
    }
}

__global__ __launch_bounds__(256) void k_block_reduce(const int* __restrict__ cnt,
                                                      int* __restrict__ bsum, int n) {
    __shared__ int sd[256];
    int i = blockIdx.x * 256 + threadIdx.x;
    sd[threadIdx.x] = (i < n) ? cnt[i] : 0;
    __syncthreads();
    for (int s = 128; s > 0; s >>= 1) {
        if (threadIdx.x < s) sd[threadIdx.x] += sd[threadIdx.x + s];
        __syncthreads();
    }
    if (threadIdx.x == 0) bsum[blockIdx.x] = sd[0];
}

// block prefix (reduce bsum[0..bid) in LDS) + in-chunk scan + dinv. nb <= 256.
__global__ __launch_bounds__(256) void k_scan_write(const int* __restrict__ cnt,
                                                    const int* __restrict__ bsum,
                                                    int* __restrict__ rowptr,
                                                    float* __restrict__ dinv,
                                                    int n, int nb) {
    __shared__ int sd[256];
    int t = threadIdx.x;
    // 1) prefix = sum of bsum[0..blockIdx.x)
    sd[t] = (t < (int)blockIdx.x && t < nb) ? bsum[t] : 0;
    __syncthreads();
    for (int s = 128; s > 0; s >>= 1) {
        if (t < s) sd[t] += sd[t + s];
        __syncthreads();
    }
    int prefix = sd[0];
    __syncthreads();
    // 2) in-chunk exclusive scan
    int i = blockIdx.x * 256 + t;
    int v = (i < n) ? cnt[i] : 0;
    sd[t] = v;
    __syncthreads();
    for (int off = 1; off < 256; off <<= 1) {
        int add = (t >= off) ? sd[t - off] : 0;
        __syncthreads();
        sd[t] += add;
        __syncthreads();
    }
    int excl = sd[t] - v + prefix;
    if (i < n) {
        rowptr[i] = excl;
        dinv[i] = rsqrtf((float)v + 1.0f);  // +1 self-loop, always > 0
    }
}

// no atomics: pos = rowptr[d] + rank[e]; payload = {src, bits(dinv[s]*dinv[d])}
__global__ __launch_bounds__(256) void k_scatter(const int* __restrict__ src,
                                                 const int* __restrict__ dst,
                                                 const int* __restrict__ rowptr,
                                                 const int* __restrict__ rank,
                                                 const float* __restrict__ dinv,
                                                 int2* __restrict__ eSW, int E) {
    int e4 = (blockIdx.x * 256 + threadIdx.x) * 4;
    if (e4 + 3 < E) {
        int4 s = *reinterpret_cast<const int4*>(&src[e4]);
        int4 d = *reinterpret_cast<const int4*>(&dst[e4]);
        int4 r = *reinterpret_cast<const int4*>(&rank[e4]);
        int2 p0, p1, p2, p3;
        p0.x = s.x; p0.y = __float_as_int(dinv[s.x] * dinv[d.x]);
        p1.x = s.y; p1.y = __float_as_int(dinv[s.y] * dinv[d.y]);
        p2.x = s.z; p2.y = __float_as_int(dinv[s.z] * dinv[d.z]);
        p3.x = s.w; p3.y = __float_as_int(dinv[s.w] * dinv[d.w]);
        eSW[rowptr[d.x] + r.x] = p0;
        eSW[rowptr[d.y] + r.y] = p1;
        eSW[rowptr[d.z] + r.z] = p2;
        eSW[rowptr[d.w] + r.w] = p3;
    } else {
        for (int e = e4; e < E; e++) {
            int s = src[e], d = dst[e];
            int2 pp; pp.x = s; pp.y = __float_as_int(dinv[s] * dinv[d]);
            eSW[rowptr[d] + rank[e]] = pp;
        }
    }
}

// ---------------- GEMM: C_bf16[n x 128] = A_f32[n x 128] @ W[128 x 128] ------
// 256 threads = 4 waves; tile 64 rows x 128 cols. K in 4 chunks of 32.
// A-chunk staged transposed As[k][row] (coalesced float4 reads), W-chunk flat.
// Thread (tr,tc): 4 rows x 8 cols, 32 FMA/k. Output packed bf16 (RNE).

#define AP 68  // padded pitch for As rows (floats)

__global__ __launch_bounds__(256, 4) void k_gemm128(const float* __restrict__ A,
                                                    const float* __restrict__ Wg,
                                                    ushort* __restrict__ C, int nrows) {
    __shared__ float As[32 * AP];    // [k][row]
    __shared__ float Ws[32 * 128];   // [k][col]
    const int tid = threadIdx.x;
    const int tc = tid & 15;         // 8 cols: tc*8 ..
    const int tr = tid >> 4;         // 4 rows: tr*4 ..
    const int r0 = blockIdx.x * 64;

    float acc[4][8];
#pragma unroll
    for (int j = 0; j < 4; j++)
#pragma unroll
        for (int c = 0; c < 8; c++) acc[j][c] = 0.0f;

    const float4* A4 = reinterpret_cast<const float4*>(A);
    const float4* Wg4 = reinterpret_cast<const float4*>(Wg);
    float4* Ws4 = reinterpret_cast<float4*>(Ws);

    const int srow = tid >> 3;       // 0..31 row within staging pass
    const int sk4 = tid & 7;         // float4 index within 32-k chunk

    for (int kc = 0; kc < 4; kc++) {
#pragma unroll
        for (int i = 0; i < 4; i++) Ws4[tid + 256 * i] = Wg4[kc * 1024 + tid + 256 * i];
#pragma unroll
        for (int pass = 0; pass < 2; pass++) {
            int rl = srow + pass * 32;
            int rg = r0 + rl;
            if (rg > nrows - 1) rg = nrows - 1;
            float4 av = A4[(size_t)rg * 32 + kc * 8 + sk4];
            int kb = sk4 * 4;
            As[(kb + 0) * AP + rl] = av.x;
            As[(kb + 1) * AP + rl] = av.y;
            As[(kb + 2) * AP + rl] = av.z;
            As[(kb + 3) * AP + rl] = av.w;
        }
        __syncthreads();

#pragma unroll 4
        for (int k = 0; k < 32; k++) {
            const float4 a = *reinterpret_cast<const float4*>(&As[k * AP + tr * 4]);
            const float4 w0 = *reinterpret_cast<const float4*>(&Ws[k * 128 + tc * 8]);
            const float4 w1 = *reinterpret_cast<const float4*>(&Ws[k * 128 + tc * 8 + 4]);
            const float av4[4] = {a.x, a.y, a.z, a.w};
            const float wv[8] = {w0.x, w0.y, w0.z, w0.w, w1.x, w1.y, w1.z, w1.w};
#pragma unroll
            for (int j = 0; j < 4; j++)
#pragma unroll
                for (int c = 0; c < 8; c++)
                    acc[j][c] = fmaf(av4[j], wv[c], acc[j][c]);
        }
        __syncthreads();
    }

#pragma unroll
    for (int j = 0; j < 4; j++) {
        const int r = r0 + tr * 4 + j;
        if (r < nrows) {
            uint4 o;
            o.x = (uint)f2bf(acc[j][0]) | ((uint)f2bf(acc[j][1]) << 16);
            o.y = (uint)f2bf(acc[j][2]) | ((uint)f2bf(acc[j][3]) << 16);
            o.z = (uint)f2bf(acc[j][4]) | ((uint)f2bf(acc[j][5]) << 16);
            o.w = (uint)f2bf(acc[j][6]) | ((uint)f2bf(acc[j][7]) << 16);
            *reinterpret_cast<uint4*>(&C[(size_t)r * 128 + tc * 8]) = o;
        }
    }
}

// ---------------- Gather (pull-style), bf16 rows, half-wave pairing ---------
// wave = 1 dst node. lane = (half, sub): half 0 even edges, half 1 odd edges;
// lane loads uint2 = 4 bf16 cols. One VMEM instr fetches TWO rows (512 B).
// Final __shfl_xor(32) combines halves. (Quarter-wave (round 11) was NOT
// faster — gather is L2/L3-throughput-bound, not issue-bound.)

__global__ __launch_bounds__(256) void k_gather(const ushort* __restrict__ hw,
                                                const float* __restrict__ dinv,
                                                const int* __restrict__ rowptr,
                                                const int* __restrict__ cnt,
                                                const int2* __restrict__ eSW,
                                                const float* __restrict__ bias,
                                                float* __restrict__ outp, int n) {
    int wave = threadIdx.x >> 6;
    int lane = threadIdx.x & 63;
    int half = lane >> 5;
    int sub = lane & 31;
    int node = blockIdx.x * 4 + wave;
    if (node >= n) return;

    float di = dinv[node];
    int start = rowptr[node];
    int deg = cnt[node];

    const uint2* base2 = reinterpret_cast<const uint2*>(hw);
    float a0, a1, a2, a3;
    {   // self-loop: half 0 only (half 1 weight 0)
        uint2 u = base2[(size_t)node * 32 + sub];
        float sw = half ? 0.0f : di * di;
        a0 = bf_lo(u.x) * sw; a1 = bf_hi(u.x) * sw;
        a2 = bf_lo(u.y) * sw; a3 = bf_hi(u.y) * sw;
    }

    int j = 0;
    for (; j + 8 <= deg; j += 8) {           // 4 full pairs, no predication
        int2 e[4]; uint2 u[4];
#pragma unroll
        for (int t = 0; t < 4; t++) e[t] = eSW[start + j + 2 * t + half];
#pragma unroll
        for (int t = 0; t < 4; t++) u[t] = base2[(size_t)e[t].x * 32 + sub];
#pragma unroll
        for (int t = 0; t < 4; t++) {
            float w = __int_as_float(e[t].y);
            a0 = fmaf(bf_lo(u[t].x), w, a0);
            a1 = fmaf(bf_hi(u[t].x), w, a1);
            a2 = fmaf(bf_lo(u[t].y), w, a2);
            a3 = fmaf(bf_hi(u[t].y), w, a3);
        }
    }
    for (; j < deg; j += 2) {                // tail pairs, predicated
        int idx = j + half;
        bool ok = idx < deg;
        int2 e = eSW[start + (ok ? idx : deg - 1)];
        float w = ok ? __int_as_float(e.y) : 0.0f;
        uint2 u = base2[(size_t)e.x * 32 + sub];
        a0 = fmaf(bf_lo(u.x), w, a0);
        a1 = fmaf(bf_hi(u.x), w, a1);
        a2 = fmaf(bf_lo(u.y), w, a2);
        a3 = fmaf(bf_hi(u.y), w, a3);
    }

    // combine halves
    a0 += __shfl_xor(a0, 32);
    a1 += __shfl_xor(a1, 32);
    a2 += __shfl_xor(a2, 32);
    a3 += __shfl_xor(a3, 32);

    if (half == 0) {
        float4 bb = reinterpret_cast<const float4*>(bias)[sub];
        float4 o;
        o.x = fmaxf(a0 + bb.x, 0.0f);
        o.y = fmaxf(a1 + bb.y, 0.0f);
        o.z = fmaxf(a2 + bb.z, 0.0f);
        o.w = fmaxf(a3 + bb.w, 0.0f);
        reinterpret_cast<float4*>(outp + (size_t)node * 128)[sub] = o;
    }
}

// ---------------- Gather #2 fused with max-pool (same structure) ------------

__global__ __launch_bounds__(256) void k_gather_pool(const ushort* __restrict__ hw,
                                                     const float* __restrict__ dinv,
                                                     const int* __restrict__ rowptr,
                                                     const int* __restrict__ cnt,
                                                     const int2* __restrict__ eSW,
                                                     const float* __restrict__ bias,
                                                     int* __restrict__ pooledPart, int n) {
    __shared__ int smax[128];
    int tid = threadIdx.x;
    int wave = tid >> 6;
    int lane = tid & 63;
    int half = lane >> 5;
    int sub = lane & 31;
    if (tid < 128) smax[tid] = 0;
    __syncthreads();

    int node = blockIdx.x * 4 + wave;
    if (node < n) {
        float di = dinv[node];
        int start = rowptr[node];
        int deg = cnt[node];

        const uint2* base2 = reinterpret_cast<const uint2*>(hw);
        float a0, a1, a2, a3;
        {
            uint2 u = base2[(size_t)node * 32 + sub];
            float sw = half ? 0.0f : di * di;
            a0 = bf_lo(u.x) * sw; a1 = bf_hi(u.x) * sw;
            a2 = bf_lo(u.y) * sw; a3 = bf_hi(u.y) * sw;
        }

        int j = 0;
        for (; j + 8 <= deg; j += 8) {
            int2 e[4]; uint2 u[4];
#pragma unroll
            for (int t = 0; t < 4; t++) e[t] = eSW[start + j + 2 * t + half];
#pragma unroll
            for (int t = 0; t < 4; t++) u[t] = base2[(size_t)e[t].x * 32 + sub];
#pragma unroll
            for (int t = 0; t < 4; t++) {
                float w = __int_as_float(e[t].y);
                a0 = fmaf(bf_lo(u[t].x), w, a0);
                a1 = fmaf(bf_hi(u[t].x), w, a1);
                a2 = fmaf(bf_lo(u[t].y), w, a2);
                a3 = fmaf(bf_hi(u[t].y), w, a3);
            }
        }
        for (; j < deg; j += 2) {
            int idx = j + half;
            bool ok = idx < deg;
            int2 e = eSW[start + (ok ? idx : deg - 1)];
            float w = ok ? __int_as_float(e.y) : 0.0f;
            uint2 u = base2[(size_t)e.x * 32 + sub];
            a0 = fmaf(bf_lo(u.x), w, a0);
            a1 = fmaf(bf_hi(u.x), w, a1);
            a2 = fmaf(bf_lo(u.y), w, a2);
            a3 = fmaf(bf_hi(u.y), w, a3);
        }

        a0 += __shfl_xor(a0, 32);
        a1 += __shfl_xor(a1, 32);
        a2 += __shfl_xor(a2, 32);
        a3 += __shfl_xor(a3, 32);

        if (half == 0) {
            float4 bb = reinterpret_cast<const float4*>(bias)[sub];
            a0 = fmaxf(a0 + bb.x, 0.0f);   // ReLU -> >= 0, int-max trick valid
            a1 = fmaxf(a1 + bb.y, 0.0f);
            a2 = fmaxf(a2 + bb.z, 0.0f);
            a3 = fmaxf(a3 + bb.w, 0.0f);
            atomicMax(&smax[sub * 4 + 0], __float_as_int(a0));
            atomicMax(&smax[sub * 4 + 1], __float_as_int(a1));
            atomicMax(&smax[sub * 4 + 2], __float_as_int(a2));
            atomicMax(&smax[sub * 4 + 3], __float_as_int(a3));
        }
    }
    __syncthreads();
    if (tid < 128) pooledPart[(size_t)blockIdx.x * 128 + tid] = smax[tid];
}

// ---------------- pool reduce + fc, fused (last-block-done ticket) ----------
// pooledBits needs NO memset: 0xAA poison = negative int, all values >= 0 win.
// ticket IS zeroed (shares the cnt memset region).

__global__ __launch_bounds__(256) void k_pool2fc(const int* __restrict__ pooledPart,
                                                 int* __restrict__ pooledBits,
                                                 int* __restrict__ ticket,
                                                 const float* __restrict__ Wfc,
                                                 const float* __restrict__ bfc,
                                                 float* __restrict__ out, int nPart) {
    __shared__ int smax[128];
    __shared__ int isLast;
    int tid = threadIdx.x;
    int c = tid & 127;
    int rh = tid >> 7;
    if (tid < 128) smax[tid] = 0;
    __syncthreads();
    int m = 0;
    for (int p = blockIdx.x * 2 + rh; p < nPart; p += gridDim.x * 2) {
        int v = pooledPart[(size_t)p * 128 + c];
        m = v > m ? v : m;   // post-ReLU bits: int compare == float compare
    }
    atomicMax(&smax[c], m);
    __syncthreads();
    if (tid < 128) atomicMax(&pooledBits[tid], smax[tid]);
    __threadfence();
    if (tid == 0) isLast = (atomicAdd(ticket, 1) == (int)gridDim.x - 1) ? 1 : 0;
    __syncthreads();
    if (isLast) {
        __threadfence();
        if (tid < 128) smax[tid] = atomicMax(&pooledBits[tid], 0);  // coherent read
        __syncthreads();
        if (tid < 64) {
            float acc = bfc[tid];
            for (int k = 0; k < 128; k++)
                acc = fmaf(__int_as_float(smax[k]), Wfc[k * 64 + tid], acc);
            out[tid] = acc;
        }
    }
}

// ---------------- launch ----------------

extern "C" void kernel_launch(void* const* d_in, const int* in_sizes, int n_in,
                              void* d_out, int out_size, void* d_ws, size_t ws_size,
                              hipStream_t stream) {
    const float* x   = (const float*)d_in[0];
    const int* edges = (const int*)d_in[1];
    const float* W1  = (const float*)d_in[2];
    const float* b1  = (const float*)d_in[3];
    const float* W2  = (const float*)d_in[4];
    const float* b2  = (const float*)d_in[5];
    const float* Wfc = (const float*)d_in[6];
    const float* bfc = (const float*)d_in[7];
    float* out = (float*)d_out;

    const int N = in_sizes[0] / 128;
    const int E = in_sizes[1] / 2;
    const int* esrc_in = edges;       // edge_index[0]
    const int* edst_in = edges + E;   // edge_index[1]

    // workspace layout (256B aligned chunks)
    auto align256 = [](size_t v) { return (v + 255) & ~(size_t)255; };
    char* p = (char*)d_ws;
    size_t off = 0;
    int* cnt      = (int*)(p + off); off += (size_t)N * 4;
    int* ticket   = (int*)(p + off); off = align256(off + 4);      // zeroed with cnt
    int* rowptr   = (int*)(p + off); off = align256(off + (size_t)N * 4);
    int* rank     = (int*)(p + off); off = align256(off + (size_t)E * 4);
    float* dinv   = (float*)(p + off); off = align256(off + (size_t)N * 4);
    int* bsum     = (int*)(p + off); off = align256(off + 256 * 4);
    int* pooled   = (int*)(p + off); off = align256(off + 128 * 4);
    int2* eSW     = (int2*)(p + off); off = align256(off + (size_t)E * 8);
    ushort* hwbuf = (ushort*)(p + off); off = align256(off + (size_t)N * 128 * 2);  // bf16 hw
    float* hbuf   = (float*)(p + off); off = align256(off + (size_t)N * 128 * 4);   // fp32 h1
    (void)ws_size; (void)n_in; (void)out_size;

    const int EB4 = (E / 4 + 255) / 256;  // edge blocks, 4 edges/thread
    const int NB = (N + 255) / 256;       // node blocks (<=256 for bsum scan)
    const int GB = (N + 63) / 64;         // gemm blocks (64 rows each)
    const int HB = (N + 3) / 4;           // gather blocks (4 nodes each)

    int* pooledPart = (int*)hbuf;         // reuse: 2nd gather no longer writes h

    hipMemsetAsync(cnt, 0, (size_t)N * 4 + 4, stream);  // cnt + ticket

    k_count<<<EB4, 256, 0, stream>>>(edst_in, cnt, rank, E);
    k_block_reduce<<<NB, 256, 0, stream>>>(cnt, bsum, N);
    k_scan_write<<<NB, 256, 0, stream>>>(cnt, bsum, rowptr, dinv, N, NB);
    k_scatter<<<EB4, 256, 0, stream>>>(esrc_in, edst_in, rowptr, rank, dinv, eSW, E);

    // layer 1
    k_gemm128<<<GB, 256, 0, stream>>>(x, W1, hwbuf, N);
    k_gather<<<HB, 256, 0, stream>>>(hwbuf, dinv, rowptr, cnt, eSW, b1, hbuf, N);
    // layer 2
    k_gemm128<<<GB, 256, 0, stream>>>(hbuf, W2, hwbuf, N);
    k_gather_pool<<<HB, 256, 0, stream>>>(hwbuf, dinv, rowptr, cnt, eSW, b2, pooledPart, N);

    // pool reduce + fc (fused)
    k_pool2fc<<<128, 256, 0, stream>>>(pooledPart, pooled, ticket, Wfc, bfc, out, HB);
}

// Round 13
// 298.770 us; speedup vs baseline: 1.0863x; 1.0350x over previous
//
#include <hip/hip_runtime.h>
#include <cstdint>
#include <cstddef>

typedef unsigned int uint;
typedef unsigned short ushort;

// bf16 helpers: RNE pack, shift-unpack (exact)
__device__ __forceinline__ ushort f2bf(float f) {
    uint u = __float_as_uint(f);
    u = u + 0x7FFFu + ((u >> 16) & 1u);
    return (ushort)(u >> 16);
}
__device__ __forceinline__ float bf_lo(uint u) { return __uint_as_float((u & 0xFFFFu) << 16); }
__device__ __forceinline__ float bf_hi(uint u) { return __uint_as_float(u & 0xFFFF0000u); }

// ---------------- CSR build ----------------
// (coop grid.sync ~60-70us/barrier on MI355X (round 7) — separate kernels.
//  Rank trick (round 9): count's atomicAdd RETURN is the edge's rank ->
//  scatter has no atomics. Round 11 lesson: keep the bsum 2-kernel scan.
//  Round 12: eSW packed to 4B {src:16|deg_s:16}; weights reconstructed as
//  rsqrtf((ds+1)(dd+1)) in the gather — dinv array deleted.)

__global__ __launch_bounds__(256) void k_count(const int* __restrict__ dst,
                                               int* __restrict__ cnt,
                                               int* __restrict__ rank, int E) {
    int e8 = (blockIdx.x * 256 + threadIdx.x) * 8;
    if (e8 + 7 < E) {
        int4 d0 = *reinterpret_cast<const int4*>(&dst[e8]);
        int4 d1 = *reinterpret_cast<const int4*>(&dst[e8 + 4]);
        int4 r0, r1;
        r0.x = atomicAdd(&cnt[d0.x], 1);
        r0.y = atomicAdd(&cnt[d0.y], 1);
        r0.z = atomicAdd(&cnt[d0.z], 1);
        r0.w = atomicAdd(&cnt[d0.w], 1);
        r1.x = atomicAdd(&cnt[d1.x], 1);
        r1.y = atomicAdd(&cnt[d1.y], 1);
        r1.z = atomicAdd(&cnt[d1.z], 1);
        r1.w = atomicAdd(&cnt[d1.w], 1);
        *reinterpret_cast<int4*>(&rank[e8]) = r0;       // coalesced 16B
        *reinterpret_cast<int4*>(&rank[e8 + 4]) = r1;
    } else {
        for (int e = e8; e < E; e++)
            rank[e] = atomicAdd(&cnt[dst[e]], 1);
    }
}

__global__ __launch_bounds__(256) void k_block_reduce(const int* __restrict__ cnt,
                                                      int* __restrict__ bsum, int n) {
    __shared__ int sd[256];
    int i = blockIdx.x * 256 + threadIdx.x;
    sd[threadIdx.x] = (i < n) ? cnt[i] : 0;
    __syncthreads();
    for (int s = 128; s > 0; s >>= 1) {
        if (threadIdx.x < s) sd[threadIdx.x] += sd[threadIdx.x + s];
        __syncthreads();
    }
    if (threadIdx.x == 0) bsum[blockIdx.x] = sd[0];
}

// block prefix (reduce bsum[0..bid) in LDS) + in-chunk scan. nb <= 256.
__global__ __launch_bounds__(256) void k_scan_write(const int* __restrict__ cnt,
                                                    const int* __restrict__ bsum,
                                                    int* __restrict__ rowptr,
                                                    int n, int nb) {
    __shared__ int sd[256];
    int t = threadIdx.x;
    // 1) prefix = sum of bsum[0..blockIdx.x)
    sd[t] = (t < (int)blockIdx.x && t < nb) ? bsum[t] : 0;
    __syncthreads();
    for (int s = 128; s > 0; s >>= 1) {
        if (t < s) sd[t] += sd[t + s];
        __syncthreads();
    }
    int prefix = sd[0];
    __syncthreads();
    // 2) in-chunk exclusive scan
    int i = blockIdx.x * 256 + t;
    int v = (i < n) ? cnt[i] : 0;
    sd[t] = v;
    __syncthreads();
    for (int off = 1; off < 256; off <<= 1) {
        int add = (t >= off) ? sd[t - off] : 0;
        __syncthreads();
        sd[t] += add;
        __syncthreads();
    }
    if (i < n) rowptr[i] = sd[t] - v + prefix;
}

// no atomics: pos = rowptr[d] + rank[e]; payload = src | (deg_s << 16)
// (N = 50000 < 2^16; deg << 2^16)
__global__ __launch_bounds__(256) void k_scatter(const int* __restrict__ src,
                                                 const int* __restrict__ dst,
                                                 const int* __restrict__ rowptr,
                                                 const int* __restrict__ rank,
                                                 const int* __restrict__ cnt,
                                                 uint* __restrict__ eSW, int E) {
    int e4 = (blockIdx.x * 256 + threadIdx.x) * 4;
    if (e4 + 3 < E) {
        int4 s = *reinterpret_cast<const int4*>(&src[e4]);
        int4 d = *reinterpret_cast<const int4*>(&dst[e4]);
        int4 r = *reinterpret_cast<const int4*>(&rank[e4]);
        eSW[rowptr[d.x] + r.x] = (uint)s.x | ((uint)cnt[s.x] << 16);
        eSW[rowptr[d.y] + r.y] = (uint)s.y | ((uint)cnt[s.y] << 16);
        eSW[rowptr[d.z] + r.z] = (uint)s.z | ((uint)cnt[s.z] << 16);
        eSW[rowptr[d.w] + r.w] = (uint)s.w | ((uint)cnt[s.w] << 16);
    } else {
        for (int e = e4; e < E; e++) {
            int s = src[e], d = dst[e];
            eSW[rowptr[d] + rank[e]] = (uint)s | ((uint)cnt[s] << 16);
        }
    }
}

// ---------------- GEMM: C_bf16[n x 128] = A_f32[n x 128] @ W[128 x 128] ------
// 256 threads = 4 waves; tile 64 rows x 128 cols. K in 4 chunks of 32.
// A-chunk staged transposed As[k][row] (coalesced float4 reads), W-chunk flat.
// Thread (tr,tc): 4 rows x 8 cols, 32 FMA/k. Output packed bf16 (RNE).

#define AP 68  // padded pitch for As rows (floats)

__global__ __launch_bounds__(256, 4) void k_gemm128(const float* __restrict__ A,
                                                    const float* __restrict__ Wg,
                                                    ushort* __restrict__ C, int nrows) {
    __shared__ float As[32 * AP];    // [k][row]
    __shared__ float Ws[32 * 128];   // [k][col]
    const int tid = threadIdx.x;
    const int tc = tid & 15;         // 8 cols: tc*8 ..
    const int tr = tid >> 4;         // 4 rows: tr*4 ..
    const int r0 = blockIdx.x * 64;

    float acc[4][8];
#pragma unroll
    for (int j = 0; j < 4; j++)
#pragma unroll
        for (int c = 0; c < 8; c++) acc[j][c] = 0.0f;

    const float4* A4 = reinterpret_cast<const float4*>(A);
    const float4* Wg4 = reinterpret_cast<const float4*>(Wg);
    float4* Ws4 = reinterpret_cast<float4*>(Ws);

    const int srow = tid >> 3;       // 0..31 row within staging pass
    const int sk4 = tid & 7;         // float4 index within 32-k chunk

    for (int kc = 0; kc < 4; kc++) {
#pragma unroll
        for (int i = 0; i < 4; i++) Ws4[tid + 256 * i] = Wg4[kc * 1024 + tid + 256 * i];
#pragma unroll
        for (int pass = 0; pass < 2; pass++) {
            int rl = srow + pass * 32;
            int rg = r0 + rl;
            if (rg > nrows - 1) rg = nrows - 1;
            float4 av = A4[(size_t)rg * 32 + kc * 8 + sk4];
            int kb = sk4 * 4;
            As[(kb + 0) * AP + rl] = av.x;
            As[(kb + 1) * AP + rl] = av.y;
            As[(kb + 2) * AP + rl] = av.z;
            As[(kb + 3) * AP + rl] = av.w;
        }
        __syncthreads();

#pragma unroll 4
        for (int k = 0; k < 32; k++) {
            const float4 a = *reinterpret_cast<const float4*>(&As[k * AP + tr * 4]);
            const float4 w0 = *reinterpret_cast<const float4*>(&Ws[k * 128 + tc * 8]);
            const float4 w1 = *reinterpret_cast<const float4*>(&Ws[k * 128 + tc * 8 + 4]);
            const float av4[4] = {a.x, a.y, a.z, a.w};
            const float wv[8] = {w0.x, w0.y, w0.z, w0.w, w1.x, w1.y, w1.z, w1.w};
#pragma unroll
            for (int j = 0; j < 4; j++)
#pragma unroll
                for (int c = 0; c < 8; c++)
                    acc[j][c] = fmaf(av4[j], wv[c], acc[j][c]);
        }
        __syncthreads();
    }

#pragma unroll
    for (int j = 0; j < 4; j++) {
        const int r = r0 + tr * 4 + j;
        if (r < nrows) {
            uint4 o;
            o.x = (uint)f2bf(acc[j][0]) | ((uint)f2bf(acc[j][1]) << 16);
            o.y = (uint)f2bf(acc[j][2]) | ((uint)f2bf(acc[j][3]) << 16);
            o.z = (uint)f2bf(acc[j][4]) | ((uint)f2bf(acc[j][5]) << 16);
            o.w = (uint)f2bf(acc[j][6]) | ((uint)f2bf(acc[j][7]) << 16);
            *reinterpret_cast<uint4*>(&C[(size_t)r * 128 + tc * 8]) = o;
        }
    }
}

// ---------------- Gather (pull-style), bf16 rows, half-wave pairing ---------
// wave = 1 dst node. lane = (half, sub): half 0 even edges, half 1 odd edges;
// lane loads uint2 = 4 bf16 cols. One VMEM instr fetches TWO rows (512 B).
// Edge weight w = rsqrtf((deg_s+1)(deg_d+1)) reconstructed from the packed
// eSW (3 VALU ops; VALU only ~27% busy). __shfl_xor(32) combines halves.

__global__ __launch_bounds__(256) void k_gather(const ushort* __restrict__ hw,
                                                const int* __restrict__ rowptr,
                                                const int* __restrict__ cnt,
                                                const uint* __restrict__ eSW,
                                                const float* __restrict__ bias,
                                                float* __restrict__ outp, int n) {
    int wave = threadIdx.x >> 6;
    int lane = threadIdx.x & 63;
    int half = lane >> 5;
    int sub = lane & 31;
    int node = blockIdx.x * 4 + wave;
    if (node >= n) return;

    int start = rowptr[node];
    int deg = cnt[node];
    float dd1 = (float)(deg + 1);
    float di = rsqrtf(dd1);

    const uint2* base2 = reinterpret_cast<const uint2*>(hw);
    float a0, a1, a2, a3;
    {   // self-loop: half 0 only (half 1 weight 0)
        uint2 u = base2[(size_t)node * 32 + sub];
        float sw = half ? 0.0f : di * di;
        a0 = bf_lo(u.x) * sw; a1 = bf_hi(u.x) * sw;
        a2 = bf_lo(u.y) * sw; a3 = bf_hi(u.y) * sw;
    }

    int j = 0;
    for (; j + 8 <= deg; j += 8) {           // 4 full pairs, no predication
        uint e[4]; uint2 u[4];
#pragma unroll
        for (int t = 0; t < 4; t++) e[t] = eSW[start + j + 2 * t + half];
#pragma unroll
        for (int t = 0; t < 4; t++) u[t] = base2[(size_t)(e[t] & 0xFFFFu) * 32 + sub];
#pragma unroll
        for (int t = 0; t < 4; t++) {
            float w = rsqrtf((float)((e[t] >> 16) + 1u) * dd1);
            a0 = fmaf(bf_lo(u[t].x), w, a0);
            a1 = fmaf(bf_hi(u[t].x), w, a1);
            a2 = fmaf(bf_lo(u[t].y), w, a2);
            a3 = fmaf(bf_hi(u[t].y), w, a3);
        }
    }
    for (; j < deg; j += 2) {                // tail pairs, predicated
        int idx = j + half;
        bool ok = idx < deg;
        uint e = eSW[start + (ok ? idx : deg - 1)];
        float w = ok ? rsqrtf((float)((e >> 16) + 1u) * dd1) : 0.0f;
        uint2 u = base2[(size_t)(e & 0xFFFFu) * 32 + sub];
        a0 = fmaf(bf_lo(u.x), w, a0);
        a1 = fmaf(bf_hi(u.x), w, a1);
        a2 = fmaf(bf_lo(u.y), w, a2);
        a3 = fmaf(bf_hi(u.y), w, a3);
    }

    // combine halves
    a0 += __shfl_xor(a0, 32);
    a1 += __shfl_xor(a1, 32);
    a2 += __shfl_xor(a2, 32);
    a3 += __shfl_xor(a3, 32);

    if (half == 0) {
        float4 bb = reinterpret_cast<const float4*>(bias)[sub];
        float4 o;
        o.x = fmaxf(a0 + bb.x, 0.0f);
        o.y = fmaxf(a1 + bb.y, 0.0f);
        o.z = fmaxf(a2 + bb.z, 0.0f);
        o.w = fmaxf(a3 + bb.w, 0.0f);
        reinterpret_cast<float4*>(outp + (size_t)node * 128)[sub] = o;
    }
}

// ---------------- Gather #2 fused with max-pool (same structure) ------------

__global__ __launch_bounds__(256) void k_gather_pool(const ushort* __restrict__ hw,
                                                     const int* __restrict__ rowptr,
                                                     const int* __restrict__ cnt,
                                                     const uint* __restrict__ eSW,
                                                     const float* __restrict__ bias,
                                                     int* __restrict__ pooledPart, int n) {
    __shared__ int smax[128];
    int tid = threadIdx.x;
    int wave = tid >> 6;
    int lane = tid & 63;
    int half = lane >> 5;
    int sub = lane & 31;
    if (tid < 128) smax[tid] = 0;
    __syncthreads();

    int node = blockIdx.x * 4 + wave;
    if (node < n) {
        int start = rowptr[node];
        int deg = cnt[node];
        float dd1 = (float)(deg + 1);
        float di = rsqrtf(dd1);

        const uint2* base2 = reinterpret_cast<const uint2*>(hw);
        float a0, a1, a2, a3;
        {
            uint2 u = base2[(size_t)node * 32 + sub];
            float sw = half ? 0.0f : di * di;
            a0 = bf_lo(u.x) * sw; a1 = bf_hi(u.x) * sw;
            a2 = bf_lo(u.y) * sw; a3 = bf_hi(u.y) * sw;
        }

        int j = 0;
        for (; j + 8 <= deg; j += 8) {
            uint e[4]; uint2 u[4];
#pragma unroll
            for (int t = 0; t < 4; t++) e[t] = eSW[start + j + 2 * t + half];
#pragma unroll
            for (int t = 0; t < 4; t++) u[t] = base2[(size_t)(e[t] & 0xFFFFu) * 32 + sub];
#pragma unroll
            for (int t = 0; t < 4; t++) {
                float w = rsqrtf((float)((e[t] >> 16) + 1u) * dd1);
                a0 = fmaf(bf_lo(u[t].x), w, a0);
                a1 = fmaf(bf_hi(u[t].x), w, a1);
                a2 = fmaf(bf_lo(u[t].y), w, a2);
                a3 = fmaf(bf_hi(u[t].y), w, a3);
            }
        }
        for (; j < deg; j += 2) {
            int idx = j + half;
            bool ok = idx < deg;
            uint e = eSW[start + (ok ? idx : deg - 1)];
            float w = ok ? rsqrtf((float)((e >> 16) + 1u) * dd1) : 0.0f;
            uint2 u = base2[(size_t)(e & 0xFFFFu) * 32 + sub];
            a0 = fmaf(bf_lo(u.x), w, a0);
            a1 = fmaf(bf_hi(u.x), w, a1);
            a2 = fmaf(bf_lo(u.y), w, a2);
            a3 = fmaf(bf_hi(u.y), w, a3);
        }

        a0 += __shfl_xor(a0, 32);
        a1 += __shfl_xor(a1, 32);
        a2 += __shfl_xor(a2, 32);
        a3 += __shfl_xor(a3, 32);

        if (half == 0) {
            float4 bb = reinterpret_cast<const float4*>(bias)[sub];
            a0 = fmaxf(a0 + bb.x, 0.0f);   // ReLU -> >= 0, int-max trick valid
            a1 = fmaxf(a1 + bb.y, 0.0f);
            a2 = fmaxf(a2 + bb.z, 0.0f);
            a3 = fmaxf(a3 + bb.w, 0.0f);
            atomicMax(&smax[sub * 4 + 0], __float_as_int(a0));
            atomicMax(&smax[sub * 4 + 1], __float_as_int(a1));
            atomicMax(&smax[sub * 4 + 2], __float_as_int(a2));
            atomicMax(&smax[sub * 4 + 3], __float_as_int(a3));
        }
    }
    __syncthreads();
    if (tid < 128) pooledPart[(size_t)blockIdx.x * 128 + tid] = smax[tid];
}

// ---------------- pool reduce + fc, fused (last-block-done ticket) ----------
// pooledBits needs NO memset: 0xAA poison = negative int, all values >= 0 win.
// ticket IS zeroed (shares the cnt memset region).

__global__ __launch_bounds__(256) void k_pool2fc(const int* __restrict__ pooledPart,
                                                 int* __restrict__ pooledBits,
                                                 int* __restrict__ ticket,
                                                 const float* __restrict__ Wfc,
                                                 const float* __restrict__ bfc,
                                                 float* __restrict__ out, int nPart) {
    __shared__ int smax[128];
    __shared__ int isLast;
    int tid = threadIdx.x;
    int c = tid & 127;
    int rh = tid >> 7;
    if (tid < 128) smax[tid] = 0;
    __syncthreads();
    int m = 0;
    for (int p = blockIdx.x * 2 + rh; p < nPart; p += gridDim.x * 2) {
        int v = pooledPart[(size_t)p * 128 + c];
        m = v > m ? v : m;   // post-ReLU bits: int compare == float compare
    }
    atomicMax(&smax[c], m);
    __syncthreads();
    if (tid < 128) atomicMax(&pooledBits[tid], smax[tid]);
    __threadfence();
    if (tid == 0) isLast = (atomicAdd(ticket, 1) == (int)gridDim.x - 1) ? 1 : 0;
    __syncthreads();
    if (isLast) {
        __threadfence();
        if (tid < 128) smax[tid] = atomicMax(&pooledBits[tid], 0);  // coherent read
        __syncthreads();
        if (tid < 64) {
            float acc = bfc[tid];
            for (int k = 0; k < 128; k++)
                acc = fmaf(__int_as_float(smax[k]), Wfc[k * 64 + tid], acc);
            out[tid] = acc;
        }
    }
}

// ---------------- launch ----------------

extern "C" void kernel_launch(void* const* d_in, const int* in_sizes, int n_in,
                              void* d_out, int out_size, void* d_ws, size_t ws_size,
                              hipStream_t stream) {
    const float* x   = (const float*)d_in[0];
    const int* edges = (const int*)d_in[1];
    const float* W1  = (const float*)d_in[2];
    const float* b1  = (const float*)d_in[3];
    const float* W2  = (const float*)d_in[4];
    const float* b2  = (const float*)d_in[5];
    const float* Wfc = (const float*)d_in[6];
    const float* bfc = (const float*)d_in[7];
    float* out = (float*)d_out;

    const int N = in_sizes[0] / 128;
    const int E = in_sizes[1] / 2;
    const int* esrc_in = edges;       // edge_index[0]
    const int* edst_in = edges + E;   // edge_index[1]

    // workspace layout (256B aligned chunks)
    auto align256 = [](size_t v) { return (v + 255) & ~(size_t)255; };
    char* p = (char*)d_ws;
    size_t off = 0;
    int* cnt      = (int*)(p + off); off += (size_t)N * 4;
    int* ticket   = (int*)(p + off); off = align256(off + 4);      // zeroed with cnt
    int* rowptr   = (int*)(p + off); off = align256(off + (size_t)N * 4);
    int* rank     = (int*)(p + off); off = align256(off + (size_t)E * 4);
    int* bsum     = (int*)(p + off); off = align256(off + 256 * 4);
    int* pooled   = (int*)(p + off); off = align256(off + 128 * 4);
    uint* eSW     = (uint*)(p + off); off = align256(off + (size_t)E * 4);
    ushort* hwbuf = (ushort*)(p + off); off = align256(off + (size_t)N * 128 * 2);  // bf16 hw
    float* hbuf   = (float*)(p + off); off = align256(off + (size_t)N * 128 * 4);   // fp32 h1
    (void)ws_size; (void)n_in; (void)out_size;

    const int EB8 = (E / 8 + 255) / 256;  // count blocks, 8 edges/thread
    const int EB4 = (E / 4 + 255) / 256;  // scatter blocks, 4 edges/thread
    const int NB = (N + 255) / 256;       // node blocks (<=256 for bsum scan)
    const int GB = (N + 63) / 64;         // gemm blocks (64 rows each)
    const int HB = (N + 3) / 4;           // gather blocks (4 nodes each)

    int* pooledPart = (int*)hbuf;         // reuse: 2nd gather no longer writes h

    hipMemsetAsync(cnt, 0, (size_t)N * 4 + 4, stream);  // cnt + ticket

    k_count<<<EB8, 256, 0, stream>>>(edst_in, cnt, rank, E);
    k_block_reduce<<<NB, 256, 0, stream>>>(cnt, bsum, N);
    k_scan_write<<<NB, 256, 0, stream>>>(cnt, bsum, rowptr, N, NB);
    k_scatter<<<EB4, 256, 0, stream>>>(esrc_in, edst_in, rowptr, rank, cnt, eSW, E);

    // layer 1
    k_gemm128<<<GB, 256, 0, stream>>>(x, W1, hwbuf, N);
    k_gather<<<HB, 256, 0, stream>>>(hwbuf, rowptr, cnt, eSW, b1, hbuf, N);
    // layer 2
    k_gemm128<<<GB, 256, 0, stream>>>(hbuf, W2, hwbuf, N);
    k_gather_pool<<<HB, 256, 0, stream>>>(hwbuf, rowptr, cnt, eSW, b2, pooledPart, N);

    // pool reduce + fc (fused)
    k_pool2fc<<<128, 256, 0, stream>>>(pooledPart, pooled, ticket, Wfc, bfc, out, HB);
}